// Round 13
// baseline (66.394 us; speedup 1.0000x reference)
//
#include <hip/hip_runtime.h>
#include <cstdint>

#define SEQ 4096
#define NH 8
#define DH 32

typedef __bf16 bf16x8 __attribute__((ext_vector_type(8)));
typedef float f32x4 __attribute__((ext_vector_type(4)));
typedef float f32x8 __attribute__((ext_vector_type(8)));
typedef float f32x16 __attribute__((ext_vector_type(16)));
typedef unsigned short u16x8 __attribute__((ext_vector_type(8)));
typedef unsigned u32x4 __attribute__((ext_vector_type(4)));
typedef unsigned u32x2 __attribute__((ext_vector_type(2)));
typedef int i32x2 __attribute__((ext_vector_type(2)));

#define MFMA16 __builtin_amdgcn_mfma_f32_16x16x32_bf16
#define MFMA32 __builtin_amdgcn_mfma_f32_32x32x16_bf16

#define QSCALE 0.25503902427f /* (1/sqrt(32)) * log2(e) */

__device__ inline bf16x8 ld_bf8(const unsigned short* p) {
    return __builtin_bit_cast(bf16x8, *(const u16x8*)p);
}
__device__ inline unsigned short bfbits(float v) {
    return __builtin_bit_cast(unsigned short, (__bf16)v);
}
__device__ inline bf16x8 cvt_f8(f32x8 v) {
    bf16x8 r;
#pragma unroll
    for (int i = 0; i < 8; i++) r[i] = (__bf16)v[i];
    return r;
}
__device__ inline unsigned cvtpk(float lo, float hi) {
    unsigned r;
    asm("v_cvt_pk_bf16_f32 %0, %1, %2" : "=v"(r) : "v"(lo), "v"(hi));
    return r;
}

// ---------------- Kernel 0: preconvert f32 -> bf16 ----------------
__global__ __launch_bounds__(256) void precvt_kernel(
    const float* __restrict__ x0, const float* __restrict__ x1, const float* __restrict__ x2,
    const float* __restrict__ w0, const float* __restrict__ w1, const float* __restrict__ w2,
    const float* __restrict__ w3,
    unsigned short* __restrict__ bx0, unsigned short* __restrict__ bx1,
    unsigned short* __restrict__ bx2, unsigned short* __restrict__ bw0,
    unsigned short* __restrict__ bw1, unsigned short* __restrict__ bw2,
    unsigned short* __restrict__ bw3) {
    const int i = blockIdx.x * 256 + threadIdx.x;
    const float* src;
    unsigned short* dst;
    int off;
    float scale = 1.0f;
    if (i < 393216) {
        const int sel = i >> 17;
        off = i & 131071;
        src = (sel == 0) ? x0 : (sel == 1) ? x1 : x2;
        dst = (sel == 0) ? bx0 : (sel == 1) ? bx1 : bx2;
        if (sel == 0) scale = QSCALE;
    } else {
        const int j = i - 393216;
        const int sel = j >> 13;
        off = j & 8191;
        src = (sel == 0) ? w0 : (sel == 1) ? w1 : (sel == 2) ? w2 : w3;
        dst = (sel == 0) ? bw0 : (sel == 1) ? bw1 : (sel == 2) ? bw2 : bw3;
    }
    f32x8 v = ((const f32x8*)src)[off];
    u16x8 r;
#pragma unroll
    for (int j = 0; j < 8; j++) r[j] = bfbits(v[j] * scale);
    ((u16x8*)dst)[off] = r;
}

// ---------------- Kernel 1: QKV projections, bf16 inputs ----------------
// 8-wave blocks, 4m x 2n tile reuse: per block 4 X-fills + 2 W-fills serve
// 8 output tiles (12KB/tile vs 20KB/tile of the old 4-wave layout) —
// attacks the measured ~16B/cyc/CU L1-fill cap on proj.
// sel 0: Q (QSCALE pre-folded). sel 1: K. sel 2: swapped operands ->
// transposed tile in-register -> contiguous Vt[h][d][n] stores.
__global__ __launch_bounds__(512, 4) void proj_bf16_kernel(
    const unsigned short* __restrict__ X0, const unsigned short* __restrict__ X1,
    const unsigned short* __restrict__ X2, const unsigned short* __restrict__ W0,
    const unsigned short* __restrict__ W1, const unsigned short* __restrict__ W2,
    const float* __restrict__ radial,
    unsigned short* __restrict__ outq, unsigned short* __restrict__ outk,
    unsigned short* __restrict__ outv) {
    const int sel = blockIdx.y;
    const unsigned short* X = (sel == 0) ? X0 : (sel == 1) ? X1 : X2;
    const unsigned short* W = (sel == 0) ? W0 : (sel == 1) ? W1 : W2;
    const int lane = threadIdx.x & 63;
    const int w = threadIdx.x >> 6;  // 0..7
    const int cl = lane & 15;
    const int h4 = lane >> 4;
    const int mw = w >> 1;           // 0..3
    const int nw = w & 1;            // 0..1
    const int m0 = (blockIdx.x >> 2) * 128 + mw * 32;
    const int n0 = (blockIdx.x & 3) * 64 + nw * 32;

    const unsigned short* xa0 = X + (m0 + cl) * 256 + h4 * 8;
    const unsigned short* xa1 = xa0 + 16 * 256;
    const unsigned short* wb0 = W + (n0 + cl) * 256 + h4 * 8;
    const unsigned short* wb1 = wb0 + 16 * 256;

    f32x4 acc00 = {0.f, 0.f, 0.f, 0.f}, acc01 = {0.f, 0.f, 0.f, 0.f};
    f32x4 acc10 = {0.f, 0.f, 0.f, 0.f}, acc11 = {0.f, 0.f, 0.f, 0.f};

    if (sel < 2) {
#pragma unroll
        for (int ksi = 0; ksi < 8; ksi++) {
            bf16x8 a0 = ld_bf8(xa0 + ksi * 32);
            bf16x8 a1 = ld_bf8(xa1 + ksi * 32);
            bf16x8 b0 = ld_bf8(wb0 + ksi * 32);
            bf16x8 b1 = ld_bf8(wb1 + ksi * 32);
            acc00 = MFMA16(a0, b0, acc00, 0, 0, 0);
            acc01 = MFMA16(a0, b1, acc01, 0, 0, 0);
            acc10 = MFMA16(a1, b0, acc10, 0, 0, 0);
            acc11 = MFMA16(a1, b1, acc11, 0, 0, 0);
        }
        unsigned short* out = (sel == 0) ? outq : outk;
#pragma unroll
        for (int am = 0; am < 2; am++) {
#pragma unroll
            for (int r = 0; r < 4; r++) {
                const int cm = m0 + am * 16 + h4 * 4 + r;
#pragma unroll
                for (int bn = 0; bn < 2; bn++) {
                    float v = am ? (bn ? acc11[r] : acc10[r]) : (bn ? acc01[r] : acc00[r]);
                    const int cn = n0 + bn * 16 + cl;
                    const int h = cn >> 5, d = cn & 31;
                    out[(h * SEQ + cm) * DH + d] = bfbits(v);
                }
            }
        }
    } else {
        // swapped: acc[wb][xa] -> value at (d = wb*16+h4*4+r, cm = m0+xa*16+cl)
#pragma unroll
        for (int ksi = 0; ksi < 8; ksi++) {
            bf16x8 a0 = ld_bf8(xa0 + ksi * 32);
            bf16x8 a1 = ld_bf8(xa1 + ksi * 32);
            bf16x8 b0 = ld_bf8(wb0 + ksi * 32);
            bf16x8 b1 = ld_bf8(wb1 + ksi * 32);
            acc00 = MFMA16(b0, a0, acc00, 0, 0, 0);
            acc01 = MFMA16(b0, a1, acc01, 0, 0, 0);
            acc10 = MFMA16(b1, a0, acc10, 0, 0, 0);
            acc11 = MFMA16(b1, a1, acc11, 0, 0, 0);
        }
        const int h = n0 >> 5;
        const float rm0 = radial[m0 + cl];
        const float rm1 = radial[m0 + 16 + cl];
#pragma unroll
        for (int wb = 0; wb < 2; wb++) {
#pragma unroll
            for (int r = 0; r < 4; r++) {
                const int d = wb * 16 + h4 * 4 + r;
                unsigned short* vrow = outv + (h * DH + d) * SEQ + m0;
                float v0 = wb ? acc10[r] : acc00[r];
                float v1 = wb ? acc11[r] : acc01[r];
                vrow[cl] = bfbits(v0 * rm0);
                vrow[16 + cl] = bfbits(v1 * rm1);
            }
        }
    }
}

// ---- fallback (small ws): proj with inline f32->bf16 conversion ----
__global__ __launch_bounds__(256) void proj_f32_kernel(
    const float* __restrict__ X0, const float* __restrict__ X1, const float* __restrict__ X2,
    const float* __restrict__ W0, const float* __restrict__ W1, const float* __restrict__ W2,
    const float* __restrict__ radial,
    unsigned short* __restrict__ outq, unsigned short* __restrict__ outk,
    unsigned short* __restrict__ outv) {
    const int sel = blockIdx.y;
    const float* X = (sel == 0) ? X0 : (sel == 1) ? X1 : X2;
    const float* W = (sel == 0) ? W0 : (sel == 1) ? W1 : W2;
    const int lane = threadIdx.x & 63;
    const int w = threadIdx.x >> 6;
    const int cl = lane & 15;
    const int h4 = lane >> 4;
    const int t = blockIdx.x * 4 + w;
    const int m0 = (t >> 3) * 32;
    const int n0 = (t & 7) * 32;

    const float* xa0 = X + (m0 + cl) * 256 + h4 * 8;
    const float* xa1 = xa0 + 16 * 256;
    const float* wb0 = W + (n0 + cl) * 256 + h4 * 8;
    const float* wb1 = wb0 + 16 * 256;

    f32x4 acc00 = {0.f, 0.f, 0.f, 0.f}, acc01 = {0.f, 0.f, 0.f, 0.f};
    f32x4 acc10 = {0.f, 0.f, 0.f, 0.f}, acc11 = {0.f, 0.f, 0.f, 0.f};
    if (sel < 2) {
#pragma unroll
        for (int ksi = 0; ksi < 8; ksi++) {
            bf16x8 a0 = cvt_f8(*(const f32x8*)(xa0 + ksi * 32));
            bf16x8 a1 = cvt_f8(*(const f32x8*)(xa1 + ksi * 32));
            bf16x8 b0 = cvt_f8(*(const f32x8*)(wb0 + ksi * 32));
            bf16x8 b1 = cvt_f8(*(const f32x8*)(wb1 + ksi * 32));
            acc00 = MFMA16(a0, b0, acc00, 0, 0, 0);
            acc01 = MFMA16(a0, b1, acc01, 0, 0, 0);
            acc10 = MFMA16(a1, b0, acc10, 0, 0, 0);
            acc11 = MFMA16(a1, b1, acc11, 0, 0, 0);
        }
        const float qs = (sel == 0) ? QSCALE : 1.0f;
        unsigned short* out = (sel == 0) ? outq : outk;
#pragma unroll
        for (int am = 0; am < 2; am++) {
#pragma unroll
            for (int r = 0; r < 4; r++) {
                const int cm = m0 + am * 16 + h4 * 4 + r;
#pragma unroll
                for (int bn = 0; bn < 2; bn++) {
                    float v = am ? (bn ? acc11[r] : acc10[r]) : (bn ? acc01[r] : acc00[r]);
                    const int cn = n0 + bn * 16 + cl;
                    const int h = cn >> 5, d = cn & 31;
                    out[(h * SEQ + cm) * DH + d] = bfbits(v * qs);
                }
            }
        }
    } else {
#pragma unroll
        for (int ksi = 0; ksi < 8; ksi++) {
            bf16x8 a0 = cvt_f8(*(const f32x8*)(xa0 + ksi * 32));
            bf16x8 a1 = cvt_f8(*(const f32x8*)(xa1 + ksi * 32));
            bf16x8 b0 = cvt_f8(*(const f32x8*)(wb0 + ksi * 32));
            bf16x8 b1 = cvt_f8(*(const f32x8*)(wb1 + ksi * 32));
            acc00 = MFMA16(b0, a0, acc00, 0, 0, 0);
            acc01 = MFMA16(b0, a1, acc01, 0, 0, 0);
            acc10 = MFMA16(b1, a0, acc10, 0, 0, 0);
            acc11 = MFMA16(b1, a1, acc11, 0, 0, 0);
        }
        const int h = n0 >> 5;
        const float rm0 = radial[m0 + cl];
        const float rm1 = radial[m0 + 16 + cl];
#pragma unroll
        for (int wb = 0; wb < 2; wb++) {
#pragma unroll
            for (int r = 0; r < 4; r++) {
                const int d = wb * 16 + h4 * 4 + r;
                unsigned short* vrow = outv + (h * DH + d) * SEQ + m0;
                float v0 = wb ? acc10[r] : acc00[r];
                float v1 = wb ? acc11[r] : acc01[r];
                vrow[cl] = bfbits(v0 * rm0);
                vrow[16 + cl] = bfbits(v1 * rm1);
            }
        }
    }
}

// ---------------- attention pieces ----------------
__device__ inline f32x16 qk_step(bf16x8 kf0, bf16x8 kf1, const bf16x8& qf0,
                                 const bf16x8& qf1) {
    f32x16 s = {0.f, 0.f, 0.f, 0.f, 0.f, 0.f, 0.f, 0.f,
                0.f, 0.f, 0.f, 0.f, 0.f, 0.f, 0.f, 0.f};
    s = MFMA32(kf0, qf0, s, 0, 0, 0);
    s = MFMA32(kf1, qf1, s, 0, 0, 0);
    return s;
}

__device__ inline void sm_pv_step(const f32x16& s, bf16x8 vt0, bf16x8 vt1,
                                  f32x16& oacc, float& ls) {
    float p[16];
#pragma unroll
    for (int r = 0; r < 16; r++) p[r] = __builtin_amdgcn_exp2f(s[r]);
    {
        float s01 = p[0] + p[1], s23 = p[2] + p[3], s45 = p[4] + p[5], s67 = p[6] + p[7];
        float s89 = p[8] + p[9], sab = p[10] + p[11], scd = p[12] + p[13], sef = p[14] + p[15];
        ls += ((s01 + s23) + (s45 + s67)) + ((s89 + sab) + (scd + sef));
    }
    unsigned a01 = cvtpk(p[0], p[1]), a23 = cvtpk(p[2], p[3]);
    unsigned a45 = cvtpk(p[4], p[5]), a67 = cvtpk(p[6], p[7]);
    i32x2 r0 = __builtin_amdgcn_permlane32_swap((int)a01, (int)a45, false, false);
    i32x2 r1 = __builtin_amdgcn_permlane32_swap((int)a23, (int)a67, false, false);
    u32x4 pb0w = {(unsigned)r0[0], (unsigned)r1[0], (unsigned)r0[1], (unsigned)r1[1]};
    unsigned a89 = cvtpk(p[8], p[9]), aab = cvtpk(p[10], p[11]);
    unsigned acd = cvtpk(p[12], p[13]), aef = cvtpk(p[14], p[15]);
    i32x2 r2 = __builtin_amdgcn_permlane32_swap((int)a89, (int)acd, false, false);
    i32x2 r3 = __builtin_amdgcn_permlane32_swap((int)aab, (int)aef, false, false);
    u32x4 pb1w = {(unsigned)r2[0], (unsigned)r3[0], (unsigned)r2[1], (unsigned)r3[1]};
    oacc = MFMA32(vt0, __builtin_bit_cast(bf16x8, pb0w), oacc, 0, 0, 0);
    oacc = MFMA32(vt1, __builtin_bit_cast(bf16x8, pb1w), oacc, 0, 0, 0);
}

// ---------------- Kernel 2: flash attention (r11 exact: best known) ----------------
// Block = 512 thr = 8 waves = ONE 128-row q-group x 8 key-eighths (512 keys,
// 16 iters); 4 independent 32-q chains per wave against shared K/V fragments.
// amdgpu_waves_per_eu(2,2) pins max occupancy -> 256-VGPR regalloc budget.
__global__ __launch_bounds__(512, 2) __attribute__((amdgpu_waves_per_eu(2, 2)))
void attn_kernel(
    const unsigned short* __restrict__ Q, const unsigned short* __restrict__ K,
    const unsigned short* __restrict__ Vt, unsigned short* __restrict__ An) {
    __shared__ float cO[7][64][16];
    __shared__ float cls[7][4][32];
    const int lane = threadIdx.x & 63;
    const int w = threadIdx.x >> 6;  // key-eighth 0..7
    const int l31 = lane & 31;
    const int hi = lane >> 5;

    // head-per-XCD remap: 256 blocks head-major (bijective: 256 = 8*32)
    int bid = blockIdx.x;
    bid = (bid & 7) * 32 + (bid >> 3);
    const int head = bid >> 5;
    const int m0 = (bid & 31) * 128;  // 128 q-rows per block

    const unsigned short* qh = Q + head * (SEQ * DH);
    const unsigned short* kh = K + head * (SEQ * DH);
    const unsigned short* vh = Vt + head * (DH * SEQ);

    bf16x8 q0[4], q1[4];
#pragma unroll
    for (int c = 0; c < 4; c++) {
        q0[c] = ld_bf8(qh + (m0 + c * 32 + l31) * DH + hi * 8);
        q1[c] = ld_bf8(qh + (m0 + c * 32 + l31) * DH + 16 + hi * 8);
    }

    f32x16 o[4];
    float ls[4];
#pragma unroll
    for (int c = 0; c < 4; c++) {
        o[c] = (f32x16){0.f, 0.f, 0.f, 0.f, 0.f, 0.f, 0.f, 0.f,
                        0.f, 0.f, 0.f, 0.f, 0.f, 0.f, 0.f, 0.f};
        ls[c] = 0.f;
    }

    const unsigned short* kp = kh + (w * 512 + l31) * DH + hi * 8;
    const unsigned short* vp = vh + l31 * SEQ + w * 512 + hi * 8;

    for (int nb = 0; nb < 16; nb++) {
        bf16x8 kc0 = ld_bf8(kp), kc1 = ld_bf8(kp + 16);
        bf16x8 vc0 = ld_bf8(vp), vc1 = ld_bf8(vp + 16);
        // staggered: chain c's VALU (softmax+pack) overlaps chain c+1's MFMAs
        f32x16 s0 = qk_step(kc0, kc1, q0[0], q1[0]);
        f32x16 s1 = qk_step(kc0, kc1, q0[1], q1[1]);
        sm_pv_step(s0, vc0, vc1, o[0], ls[0]);
        f32x16 s2 = qk_step(kc0, kc1, q0[2], q1[2]);
        sm_pv_step(s1, vc0, vc1, o[1], ls[1]);
        f32x16 s3 = qk_step(kc0, kc1, q0[3], q1[3]);
        sm_pv_step(s2, vc0, vc1, o[2], ls[2]);
        sm_pv_step(s3, vc0, vc1, o[3], ls[3]);
        kp += 32 * DH;
        vp += 32;
    }

#pragma unroll
    for (int c = 0; c < 4; c++) ls[c] += __shfl_xor(ls[c], 32);

    // combine 8 K-split partials, one chain at a time through a reused buffer
#pragma unroll
    for (int c = 0; c < 4; c++) {
        if (w > 0) {
#pragma unroll
            for (int i = 0; i < 16; i++) cO[w - 1][lane][i] = o[c][i];
            if (hi == 0) cls[w - 1][c][l31] = ls[c];
        }
        __syncthreads();
        if (w == 0) {
#pragma unroll
            for (int j = 0; j < 7; j++) {
#pragma unroll
                for (int i = 0; i < 16; i++) o[c][i] += cO[j][lane][i];
            }
        }
        __syncthreads();  // buffer reused by next chain
    }

    if (w == 0) {
#pragma unroll
        for (int c = 0; c < 4; c++) {
            float lt = ls[c];
#pragma unroll
            for (int j = 0; j < 7; j++) lt += cls[j][c][l31];
            const float inv = 1.0f / lt;
            unsigned short* op = An + (m0 + c * 32 + l31) * 256 + head * DH;
#pragma unroll
            for (int g = 0; g < 4; g++) {
                unsigned lo = cvtpk(o[c][4 * g] * inv, o[c][4 * g + 1] * inv);
                unsigned hw = cvtpk(o[c][4 * g + 2] * inv, o[c][4 * g + 3] * inv);
                *(u32x2*)(op + 8 * g + 4 * hi) = (u32x2){lo, hw};
            }
        }
    }
}

// ---------------- Kernel 3: output projection, bf16 Wo ----------------
__global__ __launch_bounds__(256, 4) void oproj_bf16_kernel(
    const unsigned short* __restrict__ An, const unsigned short* __restrict__ Wo,
    float* __restrict__ out) {
    const int lane = threadIdx.x & 63;
    const int w = threadIdx.x >> 6;
    const int cl = lane & 15;
    const int h4 = lane >> 4;
    const int t = blockIdx.x * 4 + w;
    const int m0 = (t >> 4) * 32;
    const int n0 = (t & 15) * 16;

    const unsigned short* ap0 = An + (m0 + cl) * 256 + h4 * 8;
    const unsigned short* ap1 = ap0 + 16 * 256;
    const unsigned short* wb0 = Wo + (n0 + cl) * 256 + h4 * 8;

    f32x4 acc00 = {0.f, 0.f, 0.f, 0.f}, acc10 = {0.f, 0.f, 0.f, 0.f};
#pragma unroll
    for (int ksi = 0; ksi < 8; ksi++) {
        bf16x8 a0 = ld_bf8(ap0 + ksi * 32);
        bf16x8 a1 = ld_bf8(ap1 + ksi * 32);
        bf16x8 b0 = ld_bf8(wb0 + ksi * 32);
        acc00 = MFMA16(a0, b0, acc00, 0, 0, 0);
        acc10 = MFMA16(a1, b0, acc10, 0, 0, 0);
    }
#pragma unroll
    for (int am = 0; am < 2; am++) {
#pragma unroll
        for (int r = 0; r < 4; r++) {
            const int cm = m0 + am * 16 + h4 * 4 + r;
            out[cm * 256 + n0 + cl] = am ? acc10[r] : acc00[r];
        }
    }
}

// ---- fallback oproj (f32 Wo, inline cvt) ----
__global__ __launch_bounds__(256) void oproj_f32_kernel(
    const unsigned short* __restrict__ An, const float* __restrict__ Wo,
    float* __restrict__ out) {
    const int lane = threadIdx.x & 63;
    const int w = threadIdx.x >> 6;
    const int cl = lane & 15;
    const int h4 = lane >> 4;
    const int t = blockIdx.x * 4 + w;
    const int m0 = (t >> 3) * 32;
    const int n0 = (t & 7) * 32;

    const unsigned short* ap0 = An + (m0 + cl) * 256 + h4 * 8;
    const unsigned short* ap1 = ap0 + 16 * 256;
    const float* wb0 = Wo + (n0 + cl) * 256 + h4 * 8;
    const float* wb1 = wb0 + 16 * 256;

    f32x4 acc00 = {0.f, 0.f, 0.f, 0.f}, acc01 = {0.f, 0.f, 0.f, 0.f};
    f32x4 acc10 = {0.f, 0.f, 0.f, 0.f}, acc11 = {0.f, 0.f, 0.f, 0.f};
#pragma unroll
    for (int ksi = 0; ksi < 8; ksi++) {
        bf16x8 a0 = ld_bf8(ap0 + ksi * 32);
        bf16x8 a1 = ld_bf8(ap1 + ksi * 32);
        bf16x8 b0 = cvt_f8(*(const f32x8*)(wb0 + ksi * 32));
        bf16x8 b1 = cvt_f8(*(const f32x8*)(wb1 + ksi * 32));
        acc00 = MFMA16(a0, b0, acc00, 0, 0, 0);
        acc01 = MFMA16(a0, b1, acc01, 0, 0, 0);
        acc10 = MFMA16(a1, b0, acc10, 0, 0, 0);
        acc11 = MFMA16(a1, b1, acc11, 0, 0, 0);
    }
#pragma unroll
    for (int am = 0; am < 2; am++) {
#pragma unroll
        for (int r = 0; r < 4; r++) {
            const int cm = m0 + am * 16 + h4 * 4 + r;
#pragma unroll
            for (int bn = 0; bn < 2; bn++) {
                float v = am ? (bn ? acc11[r] : acc10[r]) : (bn ? acc01[r] : acc00[r]);
                out[cm * 256 + n0 + bn * 16 + cl] = v;
            }
        }
    }
}

extern "C" void kernel_launch(void* const* d_in, const int* in_sizes, int n_in,
                              void* d_out, int out_size, void* d_ws, size_t ws_size,
                              hipStream_t stream) {
    const float* query = (const float*)d_in[0];
    const float* key_ = (const float*)d_in[1];
    const float* value = (const float*)d_in[2];
    const float* radial = (const float*)d_in[3];
    const float* Wq = (const float*)d_in[4];
    const float* Wk = (const float*)d_in[5];
    const float* Wv = (const float*)d_in[6];
    const float* Wo = (const float*)d_in[7];

    const size_t MB = 1u << 20;
    uint8_t* base = (uint8_t*)d_ws;
    unsigned short* wq = (unsigned short*)(base + 0 * MB);
    unsigned short* wk = (unsigned short*)(base + 2 * MB);
    unsigned short* wv = (unsigned short*)(base + 4 * MB);
    unsigned short* wa = (unsigned short*)(base + 6 * MB);

    if (ws_size >= (size_t)(15.5 * 1024 * 1024)) {
        unsigned short* bX0 = (unsigned short*)(base + 8 * MB);
        unsigned short* bX1 = (unsigned short*)(base + 10 * MB);
        unsigned short* bX2 = (unsigned short*)(base + 12 * MB);
        unsigned short* bWq = (unsigned short*)(base + 14 * MB);
        unsigned short* bWk = (unsigned short*)(base + 14 * MB + 128 * 1024);
        unsigned short* bWv = (unsigned short*)(base + 14 * MB + 256 * 1024);
        unsigned short* bWo = (unsigned short*)(base + 14 * MB + 384 * 1024);
        precvt_kernel<<<1664, 256, 0, stream>>>(query, key_, value, Wq, Wk, Wv, Wo,
                                                bX0, bX1, bX2, bWq, bWk, bWv, bWo);
        proj_bf16_kernel<<<dim3(128, 3), 512, 0, stream>>>(bX0, bX1, bX2, bWq, bWk, bWv,
                                                           radial, wq, wk, wv);
        attn_kernel<<<256, 512, 0, stream>>>(wq, wk, wv, wa);
        oproj_bf16_kernel<<<512, 256, 0, stream>>>(wa, bWo, (float*)d_out);
    } else {
        proj_f32_kernel<<<dim3(256, 3), 256, 0, stream>>>(query, key_, value, Wq, Wk, Wv,
                                                          radial, wq, wk, wv);
        attn_kernel<<<256, 512, 0, stream>>>(wq, wk, wv, wa);
        oproj_f32_kernel<<<256, 256, 0, stream>>>(wa, Wo, (float*)d_out);
    }
}

// Round 14
// 61.418 us; speedup vs baseline: 1.0810x; 1.0810x over previous
//
#include <hip/hip_runtime.h>
#include <cstdint>

#define SEQ 4096
#define NH 8
#define DH 32

typedef __bf16 bf16x8 __attribute__((ext_vector_type(8)));
typedef float f32x4 __attribute__((ext_vector_type(4)));
typedef float f32x8 __attribute__((ext_vector_type(8)));
typedef float f32x16 __attribute__((ext_vector_type(16)));
typedef unsigned short u16x8 __attribute__((ext_vector_type(8)));
typedef unsigned u32x4 __attribute__((ext_vector_type(4)));
typedef unsigned u32x2 __attribute__((ext_vector_type(2)));
typedef int i32x2 __attribute__((ext_vector_type(2)));

#define MFMA16 __builtin_amdgcn_mfma_f32_16x16x32_bf16
#define MFMA32 __builtin_amdgcn_mfma_f32_32x32x16_bf16

#define QSCALE 0.25503902427f /* (1/sqrt(32)) * log2(e) */

__device__ inline bf16x8 ld_bf8(const unsigned short* p) {
    return __builtin_bit_cast(bf16x8, *(const u16x8*)p);
}
__device__ inline unsigned short bfbits(float v) {
    return __builtin_bit_cast(unsigned short, (__bf16)v);
}
__device__ inline bf16x8 cvt_f8(f32x8 v) {
    bf16x8 r;
#pragma unroll
    for (int i = 0; i < 8; i++) r[i] = (__bf16)v[i];
    return r;
}
__device__ inline unsigned cvtpk(float lo, float hi) {
    unsigned r;
    asm("v_cvt_pk_bf16_f32 %0, %1, %2" : "=v"(r) : "v"(lo), "v"(hi));
    return r;
}

// ---------------- Kernel 0: preconvert f32 -> bf16 ----------------
__global__ __launch_bounds__(256) void precvt_kernel(
    const float* __restrict__ x0, const float* __restrict__ x1, const float* __restrict__ x2,
    const float* __restrict__ w0, const float* __restrict__ w1, const float* __restrict__ w2,
    const float* __restrict__ w3,
    unsigned short* __restrict__ bx0, unsigned short* __restrict__ bx1,
    unsigned short* __restrict__ bx2, unsigned short* __restrict__ bw0,
    unsigned short* __restrict__ bw1, unsigned short* __restrict__ bw2,
    unsigned short* __restrict__ bw3) {
    const int i = blockIdx.x * 256 + threadIdx.x;
    const float* src;
    unsigned short* dst;
    int off;
    float scale = 1.0f;
    if (i < 393216) {
        const int sel = i >> 17;
        off = i & 131071;
        src = (sel == 0) ? x0 : (sel == 1) ? x1 : x2;
        dst = (sel == 0) ? bx0 : (sel == 1) ? bx1 : bx2;
        if (sel == 0) scale = QSCALE;
    } else {
        const int j = i - 393216;
        const int sel = j >> 13;
        off = j & 8191;
        src = (sel == 0) ? w0 : (sel == 1) ? w1 : (sel == 2) ? w2 : w3;
        dst = (sel == 0) ? bw0 : (sel == 1) ? bw1 : (sel == 2) ? bw2 : bw3;
    }
    f32x8 v = ((const f32x8*)src)[off];
    u16x8 r;
#pragma unroll
    for (int j = 0; j < 8; j++) r[j] = bfbits(v[j] * scale);
    ((u16x8*)dst)[off] = r;
}

// ---------------- Kernel 1: QKV projections, bf16 inputs (r11 exact) ----------------
// sel 0/1: normal orientation, Q/K[h][m][d].
// sel 2: SWAPPED MFMA operands -> transposed tile in-register, so the
// Vt[h][d][n] store is 32B-contiguous per quarter-wave.
__global__ __launch_bounds__(256, 4) void proj_bf16_kernel(
    const unsigned short* __restrict__ X0, const unsigned short* __restrict__ X1,
    const unsigned short* __restrict__ X2, const unsigned short* __restrict__ W0,
    const unsigned short* __restrict__ W1, const unsigned short* __restrict__ W2,
    const float* __restrict__ radial,
    unsigned short* __restrict__ outq, unsigned short* __restrict__ outk,
    unsigned short* __restrict__ outv) {
    const int sel = blockIdx.y;
    const unsigned short* X = (sel == 0) ? X0 : (sel == 1) ? X1 : X2;
    const unsigned short* W = (sel == 0) ? W0 : (sel == 1) ? W1 : W2;
    const int lane = threadIdx.x & 63;
    const int w = threadIdx.x >> 6;
    const int cl = lane & 15;
    const int h4 = lane >> 4;
    const int t = blockIdx.x * 4 + w;
    const int m0 = (t >> 3) * 32;
    const int n0 = (t & 7) * 32;

    const unsigned short* xa0 = X + (m0 + cl) * 256 + h4 * 8;
    const unsigned short* xa1 = xa0 + 16 * 256;
    const unsigned short* wb0 = W + (n0 + cl) * 256 + h4 * 8;
    const unsigned short* wb1 = wb0 + 16 * 256;

    f32x4 acc00 = {0.f, 0.f, 0.f, 0.f}, acc01 = {0.f, 0.f, 0.f, 0.f};
    f32x4 acc10 = {0.f, 0.f, 0.f, 0.f}, acc11 = {0.f, 0.f, 0.f, 0.f};

    if (sel < 2) {
#pragma unroll
        for (int ksi = 0; ksi < 8; ksi++) {
            bf16x8 a0 = ld_bf8(xa0 + ksi * 32);
            bf16x8 a1 = ld_bf8(xa1 + ksi * 32);
            bf16x8 b0 = ld_bf8(wb0 + ksi * 32);
            bf16x8 b1 = ld_bf8(wb1 + ksi * 32);
            acc00 = MFMA16(a0, b0, acc00, 0, 0, 0);
            acc01 = MFMA16(a0, b1, acc01, 0, 0, 0);
            acc10 = MFMA16(a1, b0, acc10, 0, 0, 0);
            acc11 = MFMA16(a1, b1, acc11, 0, 0, 0);
        }
        unsigned short* out = (sel == 0) ? outq : outk;
#pragma unroll
        for (int am = 0; am < 2; am++) {
#pragma unroll
            for (int r = 0; r < 4; r++) {
                const int cm = m0 + am * 16 + h4 * 4 + r;
#pragma unroll
                for (int bn = 0; bn < 2; bn++) {
                    float v = am ? (bn ? acc11[r] : acc10[r]) : (bn ? acc01[r] : acc00[r]);
                    const int cn = n0 + bn * 16 + cl;
                    const int h = cn >> 5, d = cn & 31;
                    out[(h * SEQ + cm) * DH + d] = bfbits(v);
                }
            }
        }
    } else {
        // swapped: acc[wb][xa] -> value at (d = wb*16+h4*4+r, cm = m0+xa*16+cl)
#pragma unroll
        for (int ksi = 0; ksi < 8; ksi++) {
            bf16x8 a0 = ld_bf8(xa0 + ksi * 32);
            bf16x8 a1 = ld_bf8(xa1 + ksi * 32);
            bf16x8 b0 = ld_bf8(wb0 + ksi * 32);
            bf16x8 b1 = ld_bf8(wb1 + ksi * 32);
            acc00 = MFMA16(b0, a0, acc00, 0, 0, 0);
            acc01 = MFMA16(b0, a1, acc01, 0, 0, 0);
            acc10 = MFMA16(b1, a0, acc10, 0, 0, 0);
            acc11 = MFMA16(b1, a1, acc11, 0, 0, 0);
        }
        const int h = n0 >> 5;
        const float rm0 = radial[m0 + cl];
        const float rm1 = radial[m0 + 16 + cl];
#pragma unroll
        for (int wb = 0; wb < 2; wb++) {
#pragma unroll
            for (int r = 0; r < 4; r++) {
                const int d = wb * 16 + h4 * 4 + r;
                unsigned short* vrow = outv + (h * DH + d) * SEQ + m0;
                float v0 = wb ? acc10[r] : acc00[r];
                float v1 = wb ? acc11[r] : acc01[r];
                vrow[cl] = bfbits(v0 * rm0);
                vrow[16 + cl] = bfbits(v1 * rm1);
            }
        }
    }
}

// ---- fallback (small ws): proj with inline f32->bf16 conversion ----
__global__ __launch_bounds__(256) void proj_f32_kernel(
    const float* __restrict__ X0, const float* __restrict__ X1, const float* __restrict__ X2,
    const float* __restrict__ W0, const float* __restrict__ W1, const float* __restrict__ W2,
    const float* __restrict__ radial,
    unsigned short* __restrict__ outq, unsigned short* __restrict__ outk,
    unsigned short* __restrict__ outv) {
    const int sel = blockIdx.y;
    const float* X = (sel == 0) ? X0 : (sel == 1) ? X1 : X2;
    const float* W = (sel == 0) ? W0 : (sel == 1) ? W1 : W2;
    const int lane = threadIdx.x & 63;
    const int w = threadIdx.x >> 6;
    const int cl = lane & 15;
    const int h4 = lane >> 4;
    const int t = blockIdx.x * 4 + w;
    const int m0 = (t >> 3) * 32;
    const int n0 = (t & 7) * 32;

    const float* xa0 = X + (m0 + cl) * 256 + h4 * 8;
    const float* xa1 = xa0 + 16 * 256;
    const float* wb0 = W + (n0 + cl) * 256 + h4 * 8;
    const float* wb1 = wb0 + 16 * 256;

    f32x4 acc00 = {0.f, 0.f, 0.f, 0.f}, acc01 = {0.f, 0.f, 0.f, 0.f};
    f32x4 acc10 = {0.f, 0.f, 0.f, 0.f}, acc11 = {0.f, 0.f, 0.f, 0.f};
    if (sel < 2) {
#pragma unroll
        for (int ksi = 0; ksi < 8; ksi++) {
            bf16x8 a0 = cvt_f8(*(const f32x8*)(xa0 + ksi * 32));
            bf16x8 a1 = cvt_f8(*(const f32x8*)(xa1 + ksi * 32));
            bf16x8 b0 = cvt_f8(*(const f32x8*)(wb0 + ksi * 32));
            bf16x8 b1 = cvt_f8(*(const f32x8*)(wb1 + ksi * 32));
            acc00 = MFMA16(a0, b0, acc00, 0, 0, 0);
            acc01 = MFMA16(a0, b1, acc01, 0, 0, 0);
            acc10 = MFMA16(a1, b0, acc10, 0, 0, 0);
            acc11 = MFMA16(a1, b1, acc11, 0, 0, 0);
        }
        const float qs = (sel == 0) ? QSCALE : 1.0f;
        unsigned short* out = (sel == 0) ? outq : outk;
#pragma unroll
        for (int am = 0; am < 2; am++) {
#pragma unroll
            for (int r = 0; r < 4; r++) {
                const int cm = m0 + am * 16 + h4 * 4 + r;
#pragma unroll
                for (int bn = 0; bn < 2; bn++) {
                    float v = am ? (bn ? acc11[r] : acc10[r]) : (bn ? acc01[r] : acc00[r]);
                    const int cn = n0 + bn * 16 + cl;
                    const int h = cn >> 5, d = cn & 31;
                    out[(h * SEQ + cm) * DH + d] = bfbits(v * qs);
                }
            }
        }
    } else {
#pragma unroll
        for (int ksi = 0; ksi < 8; ksi++) {
            bf16x8 a0 = cvt_f8(*(const f32x8*)(xa0 + ksi * 32));
            bf16x8 a1 = cvt_f8(*(const f32x8*)(xa1 + ksi * 32));
            bf16x8 b0 = cvt_f8(*(const f32x8*)(wb0 + ksi * 32));
            bf16x8 b1 = cvt_f8(*(const f32x8*)(wb1 + ksi * 32));
            acc00 = MFMA16(b0, a0, acc00, 0, 0, 0);
            acc01 = MFMA16(b0, a1, acc01, 0, 0, 0);
            acc10 = MFMA16(b1, a0, acc10, 0, 0, 0);
            acc11 = MFMA16(b1, a1, acc11, 0, 0, 0);
        }
        const int h = n0 >> 5;
        const float rm0 = radial[m0 + cl];
        const float rm1 = radial[m0 + 16 + cl];
#pragma unroll
        for (int wb = 0; wb < 2; wb++) {
#pragma unroll
            for (int r = 0; r < 4; r++) {
                const int d = wb * 16 + h4 * 4 + r;
                unsigned short* vrow = outv + (h * DH + d) * SEQ + m0;
                float v0 = wb ? acc10[r] : acc00[r];
                float v1 = wb ? acc11[r] : acc01[r];
                vrow[cl] = bfbits(v0 * rm0);
                vrow[16 + cl] = bfbits(v1 * rm1);
            }
        }
    }
}

// ---------------- attention pieces ----------------
__device__ inline f32x16 qk_step(bf16x8 kf0, bf16x8 kf1, const bf16x8& qf0,
                                 const bf16x8& qf1) {
    f32x16 s = {0.f, 0.f, 0.f, 0.f, 0.f, 0.f, 0.f, 0.f,
                0.f, 0.f, 0.f, 0.f, 0.f, 0.f, 0.f, 0.f};
    s = MFMA32(kf0, qf0, s, 0, 0, 0);
    s = MFMA32(kf1, qf1, s, 0, 0, 0);
    return s;
}

__device__ inline void sm_pv_step(const f32x16& s, bf16x8 vt0, bf16x8 vt1,
                                  f32x16& oacc, float& ls) {
    float p[16];
#pragma unroll
    for (int r = 0; r < 16; r++) p[r] = __builtin_amdgcn_exp2f(s[r]);
    {
        float s01 = p[0] + p[1], s23 = p[2] + p[3], s45 = p[4] + p[5], s67 = p[6] + p[7];
        float s89 = p[8] + p[9], sab = p[10] + p[11], scd = p[12] + p[13], sef = p[14] + p[15];
        ls += ((s01 + s23) + (s45 + s67)) + ((s89 + sab) + (scd + sef));
    }
    unsigned a01 = cvtpk(p[0], p[1]), a23 = cvtpk(p[2], p[3]);
    unsigned a45 = cvtpk(p[4], p[5]), a67 = cvtpk(p[6], p[7]);
    i32x2 r0 = __builtin_amdgcn_permlane32_swap((int)a01, (int)a45, false, false);
    i32x2 r1 = __builtin_amdgcn_permlane32_swap((int)a23, (int)a67, false, false);
    u32x4 pb0w = {(unsigned)r0[0], (unsigned)r1[0], (unsigned)r0[1], (unsigned)r1[1]};
    unsigned a89 = cvtpk(p[8], p[9]), aab = cvtpk(p[10], p[11]);
    unsigned acd = cvtpk(p[12], p[13]), aef = cvtpk(p[14], p[15]);
    i32x2 r2 = __builtin_amdgcn_permlane32_swap((int)a89, (int)acd, false, false);
    i32x2 r3 = __builtin_amdgcn_permlane32_swap((int)aab, (int)aef, false, false);
    u32x4 pb1w = {(unsigned)r2[0], (unsigned)r3[0], (unsigned)r2[1], (unsigned)r3[1]};
    oacc = MFMA32(vt0, __builtin_bit_cast(bf16x8, pb0w), oacc, 0, 0, 0);
    oacc = MFMA32(vt1, __builtin_bit_cast(bf16x8, pb1w), oacc, 0, 0, 0);
}

// ---------------- Kernel 2: flash attention ----------------
// r11 structure (4 chains/wave, KSPLIT-8, waves_per_eu(2,2) pin) with ONE
// change: key-loop unrolled x2 — both 32-key fragment groups (8 loads)
// issued at the iteration top, halving load-exposure events (16 -> 8) and
// letting the second half's compute cover the first half's L2 latency.
__global__ __launch_bounds__(512, 2) __attribute__((amdgpu_waves_per_eu(2, 2)))
void attn_kernel(
    const unsigned short* __restrict__ Q, const unsigned short* __restrict__ K,
    const unsigned short* __restrict__ Vt, unsigned short* __restrict__ An) {
    __shared__ float cO[7][64][16];
    __shared__ float cls[7][4][32];
    const int lane = threadIdx.x & 63;
    const int w = threadIdx.x >> 6;  // key-eighth 0..7
    const int l31 = lane & 31;
    const int hi = lane >> 5;

    // head-per-XCD remap: 256 blocks head-major (bijective: 256 = 8*32)
    int bid = blockIdx.x;
    bid = (bid & 7) * 32 + (bid >> 3);
    const int head = bid >> 5;
    const int m0 = (bid & 31) * 128;  // 128 q-rows per block

    const unsigned short* qh = Q + head * (SEQ * DH);
    const unsigned short* kh = K + head * (SEQ * DH);
    const unsigned short* vh = Vt + head * (DH * SEQ);

    bf16x8 q0[4], q1[4];
#pragma unroll
    for (int c = 0; c < 4; c++) {
        q0[c] = ld_bf8(qh + (m0 + c * 32 + l31) * DH + hi * 8);
        q1[c] = ld_bf8(qh + (m0 + c * 32 + l31) * DH + 16 + hi * 8);
    }

    f32x16 o[4];
    float ls[4];
#pragma unroll
    for (int c = 0; c < 4; c++) {
        o[c] = (f32x16){0.f, 0.f, 0.f, 0.f, 0.f, 0.f, 0.f, 0.f,
                        0.f, 0.f, 0.f, 0.f, 0.f, 0.f, 0.f, 0.f};
        ls[c] = 0.f;
    }

    const unsigned short* kp = kh + (w * 512 + l31) * DH + hi * 8;
    const unsigned short* vp = vh + l31 * SEQ + w * 512 + hi * 8;

    for (int nb = 0; nb < 8; nb++) {
        // both 32-key groups' fragments loaded up front (8 loads)
        bf16x8 ka0 = ld_bf8(kp), ka1 = ld_bf8(kp + 16);
        bf16x8 kb0 = ld_bf8(kp + 32 * DH), kb1 = ld_bf8(kp + 32 * DH + 16);
        bf16x8 va0 = ld_bf8(vp), va1 = ld_bf8(vp + 16);
        bf16x8 vb0 = ld_bf8(vp + 32), vb1 = ld_bf8(vp + 48);
        // first 32 keys: staggered 4-chain schedule
        {
            f32x16 s0 = qk_step(ka0, ka1, q0[0], q1[0]);
            f32x16 s1 = qk_step(ka0, ka1, q0[1], q1[1]);
            sm_pv_step(s0, va0, va1, o[0], ls[0]);
            f32x16 s2 = qk_step(ka0, ka1, q0[2], q1[2]);
            sm_pv_step(s1, va0, va1, o[1], ls[1]);
            f32x16 s3 = qk_step(ka0, ka1, q0[3], q1[3]);
            sm_pv_step(s2, va0, va1, o[2], ls[2]);
            sm_pv_step(s3, va0, va1, o[3], ls[3]);
        }
        // second 32 keys
        {
            f32x16 s0 = qk_step(kb0, kb1, q0[0], q1[0]);
            f32x16 s1 = qk_step(kb0, kb1, q0[1], q1[1]);
            sm_pv_step(s0, vb0, vb1, o[0], ls[0]);
            f32x16 s2 = qk_step(kb0, kb1, q0[2], q1[2]);
            sm_pv_step(s1, vb0, vb1, o[1], ls[1]);
            f32x16 s3 = qk_step(kb0, kb1, q0[3], q1[3]);
            sm_pv_step(s2, vb0, vb1, o[2], ls[2]);
            sm_pv_step(s3, vb0, vb1, o[3], ls[3]);
        }
        kp += 64 * DH;
        vp += 64;
    }

#pragma unroll
    for (int c = 0; c < 4; c++) ls[c] += __shfl_xor(ls[c], 32);

    // combine 8 K-split partials, one chain at a time through a reused buffer
#pragma unroll
    for (int c = 0; c < 4; c++) {
        if (w > 0) {
#pragma unroll
            for (int i = 0; i < 16; i++) cO[w - 1][lane][i] = o[c][i];
            if (hi == 0) cls[w - 1][c][l31] = ls[c];
        }
        __syncthreads();
        if (w == 0) {
#pragma unroll
            for (int j = 0; j < 7; j++) {
#pragma unroll
                for (int i = 0; i < 16; i++) o[c][i] += cO[j][lane][i];
            }
        }
        __syncthreads();  // buffer reused by next chain
    }

    if (w == 0) {
#pragma unroll
        for (int c = 0; c < 4; c++) {
            float lt = ls[c];
#pragma unroll
            for (int j = 0; j < 7; j++) lt += cls[j][c][l31];
            const float inv = 1.0f / lt;
            unsigned short* op = An + (m0 + c * 32 + l31) * 256 + head * DH;
#pragma unroll
            for (int g = 0; g < 4; g++) {
                unsigned lo = cvtpk(o[c][4 * g] * inv, o[c][4 * g + 1] * inv);
                unsigned hw = cvtpk(o[c][4 * g + 2] * inv, o[c][4 * g + 3] * inv);
                *(u32x2*)(op + 8 * g + 4 * hi) = (u32x2){lo, hw};
            }
        }
    }
}

// ---------------- Kernel 3: output projection, bf16 Wo (r11 exact) ----------------
__global__ __launch_bounds__(256, 4) void oproj_bf16_kernel(
    const unsigned short* __restrict__ An, const unsigned short* __restrict__ Wo,
    float* __restrict__ out) {
    const int lane = threadIdx.x & 63;
    const int w = threadIdx.x >> 6;
    const int cl = lane & 15;
    const int h4 = lane >> 4;
    const int t = blockIdx.x * 4 + w;
    const int m0 = (t >> 4) * 32;
    const int n0 = (t & 15) * 16;

    const unsigned short* ap0 = An + (m0 + cl) * 256 + h4 * 8;
    const unsigned short* ap1 = ap0 + 16 * 256;
    const unsigned short* wb0 = Wo + (n0 + cl) * 256 + h4 * 8;

    f32x4 acc00 = {0.f, 0.f, 0.f, 0.f}, acc10 = {0.f, 0.f, 0.f, 0.f};
#pragma unroll
    for (int ksi = 0; ksi < 8; ksi++) {
        bf16x8 a0 = ld_bf8(ap0 + ksi * 32);
        bf16x8 a1 = ld_bf8(ap1 + ksi * 32);
        bf16x8 b0 = ld_bf8(wb0 + ksi * 32);
        acc00 = MFMA16(a0, b0, acc00, 0, 0, 0);
        acc10 = MFMA16(a1, b0, acc10, 0, 0, 0);
    }
#pragma unroll
    for (int am = 0; am < 2; am++) {
#pragma unroll
        for (int r = 0; r < 4; r++) {
            const int cm = m0 + am * 16 + h4 * 4 + r;
            out[cm * 256 + n0 + cl] = am ? acc10[r] : acc00[r];
        }
    }
}

// ---- fallback oproj (f32 Wo, inline cvt) ----
__global__ __launch_bounds__(256) void oproj_f32_kernel(
    const unsigned short* __restrict__ An, const float* __restrict__ Wo,
    float* __restrict__ out) {
    const int lane = threadIdx.x & 63;
    const int w = threadIdx.x >> 6;
    const int cl = lane & 15;
    const int h4 = lane >> 4;
    const int t = blockIdx.x * 4 + w;
    const int m0 = (t >> 3) * 32;
    const int n0 = (t & 7) * 32;

    const unsigned short* ap0 = An + (m0 + cl) * 256 + h4 * 8;
    const unsigned short* ap1 = ap0 + 16 * 256;
    const float* wb0 = Wo + (n0 + cl) * 256 + h4 * 8;
    const float* wb1 = wb0 + 16 * 256;

    f32x4 acc00 = {0.f, 0.f, 0.f, 0.f}, acc01 = {0.f, 0.f, 0.f, 0.f};
    f32x4 acc10 = {0.f, 0.f, 0.f, 0.f}, acc11 = {0.f, 0.f, 0.f, 0.f};
#pragma unroll
    for (int ksi = 0; ksi < 8; ksi++) {
        bf16x8 a0 = ld_bf8(ap0 + ksi * 32);
        bf16x8 a1 = ld_bf8(ap1 + ksi * 32);
        bf16x8 b0 = cvt_f8(*(const f32x8*)(wb0 + ksi * 32));
        bf16x8 b1 = cvt_f8(*(const f32x8*)(wb1 + ksi * 32));
        acc00 = MFMA16(a0, b0, acc00, 0, 0, 0);
        acc01 = MFMA16(a0, b1, acc01, 0, 0, 0);
        acc10 = MFMA16(a1, b0, acc10, 0, 0, 0);
        acc11 = MFMA16(a1, b1, acc11, 0, 0, 0);
    }
#pragma unroll
    for (int am = 0; am < 2; am++) {
#pragma unroll
        for (int r = 0; r < 4; r++) {
            const int cm = m0 + am * 16 + h4 * 4 + r;
#pragma unroll
            for (int bn = 0; bn < 2; bn++) {
                float v = am ? (bn ? acc11[r] : acc10[r]) : (bn ? acc01[r] : acc00[r]);
                out[cm * 256 + n0 + bn * 16 + cl] = v;
            }
        }
    }
}

extern "C" void kernel_launch(void* const* d_in, const int* in_sizes, int n_in,
                              void* d_out, int out_size, void* d_ws, size_t ws_size,
                              hipStream_t stream) {
    const float* query = (const float*)d_in[0];
    const float* key_ = (const float*)d_in[1];
    const float* value = (const float*)d_in[2];
    const float* radial = (const float*)d_in[3];
    const float* Wq = (const float*)d_in[4];
    const float* Wk = (const float*)d_in[5];
    const float* Wv = (const float*)d_in[6];
    const float* Wo = (const float*)d_in[7];

    const size_t MB = 1u << 20;
    uint8_t* base = (uint8_t*)d_ws;
    unsigned short* wq = (unsigned short*)(base + 0 * MB);
    unsigned short* wk = (unsigned short*)(base + 2 * MB);
    unsigned short* wv = (unsigned short*)(base + 4 * MB);
    unsigned short* wa = (unsigned short*)(base + 6 * MB);

    if (ws_size >= (size_t)(15.5 * 1024 * 1024)) {
        unsigned short* bX0 = (unsigned short*)(base + 8 * MB);
        unsigned short* bX1 = (unsigned short*)(base + 10 * MB);
        unsigned short* bX2 = (unsigned short*)(base + 12 * MB);
        unsigned short* bWq = (unsigned short*)(base + 14 * MB);
        unsigned short* bWk = (unsigned short*)(base + 14 * MB + 128 * 1024);
        unsigned short* bWv = (unsigned short*)(base + 14 * MB + 256 * 1024);
        unsigned short* bWo = (unsigned short*)(base + 14 * MB + 384 * 1024);
        precvt_kernel<<<1664, 256, 0, stream>>>(query, key_, value, Wq, Wk, Wv, Wo,
                                                bX0, bX1, bX2, bWq, bWk, bWv, bWo);
        proj_bf16_kernel<<<dim3(256, 3), 256, 0, stream>>>(bX0, bX1, bX2, bWq, bWk, bWv,
                                                           radial, wq, wk, wv);
        attn_kernel<<<256, 512, 0, stream>>>(wq, wk, wv, wa);
        oproj_bf16_kernel<<<512, 256, 0, stream>>>(wa, bWo, (float*)d_out);
    } else {
        proj_f32_kernel<<<dim3(256, 3), 256, 0, stream>>>(query, key_, value, Wq, Wk, Wv,
                                                          radial, wq, wk, wv);
        attn_kernel<<<256, 512, 0, stream>>>(wq, wk, wv, wa);
        oproj_f32_kernel<<<256, 256, 0, stream>>>(wa, Wo, (float*)d_out);
    }
}

// Round 15
// 58.410 us; speedup vs baseline: 1.1367x; 1.0515x over previous
//
#include <hip/hip_runtime.h>
#include <cstdint>

#define SEQ 4096
#define NH 8
#define DH 32

typedef __bf16 bf16x8 __attribute__((ext_vector_type(8)));
typedef float f32x4 __attribute__((ext_vector_type(4)));
typedef float f32x8 __attribute__((ext_vector_type(8)));
typedef float f32x16 __attribute__((ext_vector_type(16)));
typedef unsigned short u16x8 __attribute__((ext_vector_type(8)));
typedef unsigned u32x4 __attribute__((ext_vector_type(4)));
typedef unsigned u32x2 __attribute__((ext_vector_type(2)));
typedef int i32x2 __attribute__((ext_vector_type(2)));

#define MFMA16 __builtin_amdgcn_mfma_f32_16x16x32_bf16
#define MFMA32 __builtin_amdgcn_mfma_f32_32x32x16_bf16

#define QSCALE 0.25503902427f /* (1/sqrt(32)) * log2(e) */

__device__ inline bf16x8 ld_bf8(const unsigned short* p) {
    return __builtin_bit_cast(bf16x8, *(const u16x8*)p);
}
__device__ inline unsigned short bfbits(float v) {
    return __builtin_bit_cast(unsigned short, (__bf16)v);
}
__device__ inline bf16x8 cvt_f8(f32x8 v) {
    bf16x8 r;
#pragma unroll
    for (int i = 0; i < 8; i++) r[i] = (__bf16)v[i];
    return r;
}
__device__ inline unsigned cvtpk(float lo, float hi) {
    unsigned r;
    asm("v_cvt_pk_bf16_f32 %0, %1, %2" : "=v"(r) : "v"(lo), "v"(hi));
    return r;
}

// ---------------- Kernel 0: preconvert f32 -> bf16 ----------------
__global__ __launch_bounds__(256) void precvt_kernel(
    const float* __restrict__ x0, const float* __restrict__ x1, const float* __restrict__ x2,
    const float* __restrict__ w0, const float* __restrict__ w1, const float* __restrict__ w2,
    const float* __restrict__ w3,
    unsigned short* __restrict__ bx0, unsigned short* __restrict__ bx1,
    unsigned short* __restrict__ bx2, unsigned short* __restrict__ bw0,
    unsigned short* __restrict__ bw1, unsigned short* __restrict__ bw2,
    unsigned short* __restrict__ bw3) {
    const int i = blockIdx.x * 256 + threadIdx.x;
    const float* src;
    unsigned short* dst;
    int off;
    float scale = 1.0f;
    if (i < 393216) {
        const int sel = i >> 17;
        off = i & 131071;
        src = (sel == 0) ? x0 : (sel == 1) ? x1 : x2;
        dst = (sel == 0) ? bx0 : (sel == 1) ? bx1 : bx2;
        if (sel == 0) scale = QSCALE;
    } else {
        const int j = i - 393216;
        const int sel = j >> 13;
        off = j & 8191;
        src = (sel == 0) ? w0 : (sel == 1) ? w1 : (sel == 2) ? w2 : w3;
        dst = (sel == 0) ? bw0 : (sel == 1) ? bw1 : (sel == 2) ? bw2 : bw3;
    }
    f32x8 v = ((const f32x8*)src)[off];
    u16x8 r;
#pragma unroll
    for (int j = 0; j < 8; j++) r[j] = bfbits(v[j] * scale);
    ((u16x8*)dst)[off] = r;
}

// ---------------- Kernel 1: QKV projections, bf16 inputs (r11 exact) ----------------
__global__ __launch_bounds__(256, 4) void proj_bf16_kernel(
    const unsigned short* __restrict__ X0, const unsigned short* __restrict__ X1,
    const unsigned short* __restrict__ X2, const unsigned short* __restrict__ W0,
    const unsigned short* __restrict__ W1, const unsigned short* __restrict__ W2,
    const float* __restrict__ radial,
    unsigned short* __restrict__ outq, unsigned short* __restrict__ outk,
    unsigned short* __restrict__ outv) {
    const int sel = blockIdx.y;
    const unsigned short* X = (sel == 0) ? X0 : (sel == 1) ? X1 : X2;
    const unsigned short* W = (sel == 0) ? W0 : (sel == 1) ? W1 : W2;
    const int lane = threadIdx.x & 63;
    const int w = threadIdx.x >> 6;
    const int cl = lane & 15;
    const int h4 = lane >> 4;
    const int t = blockIdx.x * 4 + w;
    const int m0 = (t >> 3) * 32;
    const int n0 = (t & 7) * 32;

    const unsigned short* xa0 = X + (m0 + cl) * 256 + h4 * 8;
    const unsigned short* xa1 = xa0 + 16 * 256;
    const unsigned short* wb0 = W + (n0 + cl) * 256 + h4 * 8;
    const unsigned short* wb1 = wb0 + 16 * 256;

    f32x4 acc00 = {0.f, 0.f, 0.f, 0.f}, acc01 = {0.f, 0.f, 0.f, 0.f};
    f32x4 acc10 = {0.f, 0.f, 0.f, 0.f}, acc11 = {0.f, 0.f, 0.f, 0.f};

    if (sel < 2) {
#pragma unroll
        for (int ksi = 0; ksi < 8; ksi++) {
            bf16x8 a0 = ld_bf8(xa0 + ksi * 32);
            bf16x8 a1 = ld_bf8(xa1 + ksi * 32);
            bf16x8 b0 = ld_bf8(wb0 + ksi * 32);
            bf16x8 b1 = ld_bf8(wb1 + ksi * 32);
            acc00 = MFMA16(a0, b0, acc00, 0, 0, 0);
            acc01 = MFMA16(a0, b1, acc01, 0, 0, 0);
            acc10 = MFMA16(a1, b0, acc10, 0, 0, 0);
            acc11 = MFMA16(a1, b1, acc11, 0, 0, 0);
        }
        unsigned short* out = (sel == 0) ? outq : outk;
#pragma unroll
        for (int am = 0; am < 2; am++) {
#pragma unroll
            for (int r = 0; r < 4; r++) {
                const int cm = m0 + am * 16 + h4 * 4 + r;
#pragma unroll
                for (int bn = 0; bn < 2; bn++) {
                    float v = am ? (bn ? acc11[r] : acc10[r]) : (bn ? acc01[r] : acc00[r]);
                    const int cn = n0 + bn * 16 + cl;
                    const int h = cn >> 5, d = cn & 31;
                    out[(h * SEQ + cm) * DH + d] = bfbits(v);
                }
            }
        }
    } else {
        // swapped: acc[wb][xa] -> value at (d = wb*16+h4*4+r, cm = m0+xa*16+cl)
#pragma unroll
        for (int ksi = 0; ksi < 8; ksi++) {
            bf16x8 a0 = ld_bf8(xa0 + ksi * 32);
            bf16x8 a1 = ld_bf8(xa1 + ksi * 32);
            bf16x8 b0 = ld_bf8(wb0 + ksi * 32);
            bf16x8 b1 = ld_bf8(wb1 + ksi * 32);
            acc00 = MFMA16(b0, a0, acc00, 0, 0, 0);
            acc01 = MFMA16(b0, a1, acc01, 0, 0, 0);
            acc10 = MFMA16(b1, a0, acc10, 0, 0, 0);
            acc11 = MFMA16(b1, a1, acc11, 0, 0, 0);
        }
        const int h = n0 >> 5;
        const float rm0 = radial[m0 + cl];
        const float rm1 = radial[m0 + 16 + cl];
#pragma unroll
        for (int wb = 0; wb < 2; wb++) {
#pragma unroll
            for (int r = 0; r < 4; r++) {
                const int d = wb * 16 + h4 * 4 + r;
                unsigned short* vrow = outv + (h * DH + d) * SEQ + m0;
                float v0 = wb ? acc10[r] : acc00[r];
                float v1 = wb ? acc11[r] : acc01[r];
                vrow[cl] = bfbits(v0 * rm0);
                vrow[16 + cl] = bfbits(v1 * rm1);
            }
        }
    }
}

// ---- fallback (small ws): proj with inline f32->bf16 conversion ----
__global__ __launch_bounds__(256) void proj_f32_kernel(
    const float* __restrict__ X0, const float* __restrict__ X1, const float* __restrict__ X2,
    const float* __restrict__ W0, const float* __restrict__ W1, const float* __restrict__ W2,
    const float* __restrict__ radial,
    unsigned short* __restrict__ outq, unsigned short* __restrict__ outk,
    unsigned short* __restrict__ outv) {
    const int sel = blockIdx.y;
    const float* X = (sel == 0) ? X0 : (sel == 1) ? X1 : X2;
    const float* W = (sel == 0) ? W0 : (sel == 1) ? W1 : W2;
    const int lane = threadIdx.x & 63;
    const int w = threadIdx.x >> 6;
    const int cl = lane & 15;
    const int h4 = lane >> 4;
    const int t = blockIdx.x * 4 + w;
    const int m0 = (t >> 3) * 32;
    const int n0 = (t & 7) * 32;

    const float* xa0 = X + (m0 + cl) * 256 + h4 * 8;
    const float* xa1 = xa0 + 16 * 256;
    const float* wb0 = W + (n0 + cl) * 256 + h4 * 8;
    const float* wb1 = wb0 + 16 * 256;

    f32x4 acc00 = {0.f, 0.f, 0.f, 0.f}, acc01 = {0.f, 0.f, 0.f, 0.f};
    f32x4 acc10 = {0.f, 0.f, 0.f, 0.f}, acc11 = {0.f, 0.f, 0.f, 0.f};
    if (sel < 2) {
#pragma unroll
        for (int ksi = 0; ksi < 8; ksi++) {
            bf16x8 a0 = cvt_f8(*(const f32x8*)(xa0 + ksi * 32));
            bf16x8 a1 = cvt_f8(*(const f32x8*)(xa1 + ksi * 32));
            bf16x8 b0 = cvt_f8(*(const f32x8*)(wb0 + ksi * 32));
            bf16x8 b1 = cvt_f8(*(const f32x8*)(wb1 + ksi * 32));
            acc00 = MFMA16(a0, b0, acc00, 0, 0, 0);
            acc01 = MFMA16(a0, b1, acc01, 0, 0, 0);
            acc10 = MFMA16(a1, b0, acc10, 0, 0, 0);
            acc11 = MFMA16(a1, b1, acc11, 0, 0, 0);
        }
        const float qs = (sel == 0) ? QSCALE : 1.0f;
        unsigned short* out = (sel == 0) ? outq : outk;
#pragma unroll
        for (int am = 0; am < 2; am++) {
#pragma unroll
            for (int r = 0; r < 4; r++) {
                const int cm = m0 + am * 16 + h4 * 4 + r;
#pragma unroll
                for (int bn = 0; bn < 2; bn++) {
                    float v = am ? (bn ? acc11[r] : acc10[r]) : (bn ? acc01[r] : acc00[r]);
                    const int cn = n0 + bn * 16 + cl;
                    const int h = cn >> 5, d = cn & 31;
                    out[(h * SEQ + cm) * DH + d] = bfbits(v * qs);
                }
            }
        }
    } else {
#pragma unroll
        for (int ksi = 0; ksi < 8; ksi++) {
            bf16x8 a0 = cvt_f8(*(const f32x8*)(xa0 + ksi * 32));
            bf16x8 a1 = cvt_f8(*(const f32x8*)(xa1 + ksi * 32));
            bf16x8 b0 = cvt_f8(*(const f32x8*)(wb0 + ksi * 32));
            bf16x8 b1 = cvt_f8(*(const f32x8*)(wb1 + ksi * 32));
            acc00 = MFMA16(b0, a0, acc00, 0, 0, 0);
            acc01 = MFMA16(b0, a1, acc01, 0, 0, 0);
            acc10 = MFMA16(b1, a0, acc10, 0, 0, 0);
            acc11 = MFMA16(b1, a1, acc11, 0, 0, 0);
        }
        const int h = n0 >> 5;
        const float rm0 = radial[m0 + cl];
        const float rm1 = radial[m0 + 16 + cl];
#pragma unroll
        for (int wb = 0; wb < 2; wb++) {
#pragma unroll
            for (int r = 0; r < 4; r++) {
                const int d = wb * 16 + h4 * 4 + r;
                unsigned short* vrow = outv + (h * DH + d) * SEQ + m0;
                float v0 = wb ? acc10[r] : acc00[r];
                float v1 = wb ? acc11[r] : acc01[r];
                vrow[cl] = bfbits(v0 * rm0);
                vrow[16 + cl] = bfbits(v1 * rm1);
            }
        }
    }
}

// ---------------- attention pieces ----------------
__device__ inline f32x16 qk_step(bf16x8 kf0, bf16x8 kf1, const bf16x8& qf0,
                                 const bf16x8& qf1) {
    f32x16 s = {0.f, 0.f, 0.f, 0.f, 0.f, 0.f, 0.f, 0.f,
                0.f, 0.f, 0.f, 0.f, 0.f, 0.f, 0.f, 0.f};
    s = MFMA32(kf0, qf0, s, 0, 0, 0);
    s = MFMA32(kf1, qf1, s, 0, 0, 0);
    return s;
}

__device__ inline void sm_pv_step(const f32x16& s, bf16x8 vt0, bf16x8 vt1,
                                  f32x16& oacc, float& ls) {
    float p[16];
#pragma unroll
    for (int r = 0; r < 16; r++) p[r] = __builtin_amdgcn_exp2f(s[r]);
    {
        float s01 = p[0] + p[1], s23 = p[2] + p[3], s45 = p[4] + p[5], s67 = p[6] + p[7];
        float s89 = p[8] + p[9], sab = p[10] + p[11], scd = p[12] + p[13], sef = p[14] + p[15];
        ls += ((s01 + s23) + (s45 + s67)) + ((s89 + sab) + (scd + sef));
    }
    unsigned a01 = cvtpk(p[0], p[1]), a23 = cvtpk(p[2], p[3]);
    unsigned a45 = cvtpk(p[4], p[5]), a67 = cvtpk(p[6], p[7]);
    i32x2 r0 = __builtin_amdgcn_permlane32_swap((int)a01, (int)a45, false, false);
    i32x2 r1 = __builtin_amdgcn_permlane32_swap((int)a23, (int)a67, false, false);
    u32x4 pb0w = {(unsigned)r0[0], (unsigned)r1[0], (unsigned)r0[1], (unsigned)r1[1]};
    unsigned a89 = cvtpk(p[8], p[9]), aab = cvtpk(p[10], p[11]);
    unsigned acd = cvtpk(p[12], p[13]), aef = cvtpk(p[14], p[15]);
    i32x2 r2 = __builtin_amdgcn_permlane32_swap((int)a89, (int)acd, false, false);
    i32x2 r3 = __builtin_amdgcn_permlane32_swap((int)aab, (int)aef, false, false);
    u32x4 pb1w = {(unsigned)r2[0], (unsigned)r3[0], (unsigned)r2[1], (unsigned)r3[1]};
    oacc = MFMA32(vt0, __builtin_bit_cast(bf16x8, pb0w), oacc, 0, 0, 0);
    oacc = MFMA32(vt1, __builtin_bit_cast(bf16x8, pb1w), oacc, 0, 0, 0);
}

// ---------------- Kernel 2: flash attention, T15 cross-iteration pipeline ----------------
// r11 geometry (4 chains/wave, KSPLIT-8, waves_per_eu(2,2)) with the att[2]
// rotation: S-tiles produced in iteration n are consumed in iteration n+1.
// Unlike the intra-iteration staggers (r7/r9/r11, all collapsed by the
// pressure-driven scheduler), s_prev is live at body entry BY CONSTRUCTION —
// serializing no longer reduces liveness, so QK MFMAs (cur) genuinely overlap
// softmax VALU (prev), and each sm_pv covers the next tile's load latency.
__global__ __launch_bounds__(512, 2) __attribute__((amdgpu_waves_per_eu(2, 2)))
void attn_kernel(
    const unsigned short* __restrict__ Q, const unsigned short* __restrict__ K,
    const unsigned short* __restrict__ Vt, unsigned short* __restrict__ An) {
    __shared__ float cO[7][64][16];
    __shared__ float cls[7][4][32];
    const int lane = threadIdx.x & 63;
    const int w = threadIdx.x >> 6;  // key-eighth 0..7
    const int l31 = lane & 31;
    const int hi = lane >> 5;

    // head-per-XCD remap: 256 blocks head-major (bijective: 256 = 8*32)
    int bid = blockIdx.x;
    bid = (bid & 7) * 32 + (bid >> 3);
    const int head = bid >> 5;
    const int m0 = (bid & 31) * 128;  // 128 q-rows per block

    const unsigned short* qh = Q + head * (SEQ * DH);
    const unsigned short* kh = K + head * (SEQ * DH);
    const unsigned short* vh = Vt + head * (DH * SEQ);

    bf16x8 q0[4], q1[4];
#pragma unroll
    for (int c = 0; c < 4; c++) {
        q0[c] = ld_bf8(qh + (m0 + c * 32 + l31) * DH + hi * 8);
        q1[c] = ld_bf8(qh + (m0 + c * 32 + l31) * DH + 16 + hi * 8);
    }

    f32x16 o[4];
    float ls[4];
#pragma unroll
    for (int c = 0; c < 4; c++) {
        o[c] = (f32x16){0.f, 0.f, 0.f, 0.f, 0.f, 0.f, 0.f, 0.f,
                        0.f, 0.f, 0.f, 0.f, 0.f, 0.f, 0.f, 0.f};
        ls[c] = 0.f;
    }

    const unsigned short* kp = kh + (w * 512 + l31) * DH + hi * 8;
    const unsigned short* vp = vh + l31 * SEQ + w * 512 + hi * 8;

    // prologue: tile 0 loaded and QK'd; SM+PV deferred to the loop body
    bf16x8 kc0 = ld_bf8(kp), kc1 = ld_bf8(kp + 16);
    bf16x8 vo0 = ld_bf8(vp), vo1 = ld_bf8(vp + 16);
    f32x16 so0 = qk_step(kc0, kc1, q0[0], q1[0]);
    f32x16 so1 = qk_step(kc0, kc1, q0[1], q1[1]);
    f32x16 so2 = qk_step(kc0, kc1, q0[2], q1[2]);
    f32x16 so3 = qk_step(kc0, kc1, q0[3], q1[3]);

    for (int nb = 0; nb < 15; nb++) {
        kp += 32 * DH;
        vp += 32;
        bf16x8 kn0 = ld_bf8(kp), kn1 = ld_bf8(kp + 16);
        bf16x8 vn0 = ld_bf8(vp), vn1 = ld_bf8(vp + 16);
        // sm_pv(prev chain c) covers the loads + QK(next chain c) MFMA issue
        sm_pv_step(so0, vo0, vo1, o[0], ls[0]);
        f32x16 sn0 = qk_step(kn0, kn1, q0[0], q1[0]);
        sm_pv_step(so1, vo0, vo1, o[1], ls[1]);
        f32x16 sn1 = qk_step(kn0, kn1, q0[1], q1[1]);
        sm_pv_step(so2, vo0, vo1, o[2], ls[2]);
        f32x16 sn2 = qk_step(kn0, kn1, q0[2], q1[2]);
        sm_pv_step(so3, vo0, vo1, o[3], ls[3]);
        f32x16 sn3 = qk_step(kn0, kn1, q0[3], q1[3]);
        so0 = sn0; so1 = sn1; so2 = sn2; so3 = sn3;
        vo0 = vn0; vo1 = vn1;
    }
    // epilogue: finish tile 15
    sm_pv_step(so0, vo0, vo1, o[0], ls[0]);
    sm_pv_step(so1, vo0, vo1, o[1], ls[1]);
    sm_pv_step(so2, vo0, vo1, o[2], ls[2]);
    sm_pv_step(so3, vo0, vo1, o[3], ls[3]);

#pragma unroll
    for (int c = 0; c < 4; c++) ls[c] += __shfl_xor(ls[c], 32);

    // combine 8 K-split partials, one chain at a time through a reused buffer
#pragma unroll
    for (int c = 0; c < 4; c++) {
        if (w > 0) {
#pragma unroll
            for (int i = 0; i < 16; i++) cO[w - 1][lane][i] = o[c][i];
            if (hi == 0) cls[w - 1][c][l31] = ls[c];
        }
        __syncthreads();
        if (w == 0) {
#pragma unroll
            for (int j = 0; j < 7; j++) {
#pragma unroll
                for (int i = 0; i < 16; i++) o[c][i] += cO[j][lane][i];
            }
        }
        __syncthreads();  // buffer reused by next chain
    }

    if (w == 0) {
#pragma unroll
        for (int c = 0; c < 4; c++) {
            float lt = ls[c];
#pragma unroll
            for (int j = 0; j < 7; j++) lt += cls[j][c][l31];
            const float inv = 1.0f / lt;
            unsigned short* op = An + (m0 + c * 32 + l31) * 256 + head * DH;
#pragma unroll
            for (int g = 0; g < 4; g++) {
                unsigned lo = cvtpk(o[c][4 * g] * inv, o[c][4 * g + 1] * inv);
                unsigned hw = cvtpk(o[c][4 * g + 2] * inv, o[c][4 * g + 3] * inv);
                *(u32x2*)(op + 8 * g + 4 * hi) = (u32x2){lo, hw};
            }
        }
    }
}

// ---------------- Kernel 3: output projection, bf16 Wo (r11 exact) ----------------
__global__ __launch_bounds__(256, 4) void oproj_bf16_kernel(
    const unsigned short* __restrict__ An, const unsigned short* __restrict__ Wo,
    float* __restrict__ out) {
    const int lane = threadIdx.x & 63;
    const int w = threadIdx.x >> 6;
    const int cl = lane & 15;
    const int h4 = lane >> 4;
    const int t = blockIdx.x * 4 + w;
    const int m0 = (t >> 4) * 32;
    const int n0 = (t & 15) * 16;

    const unsigned short* ap0 = An + (m0 + cl) * 256 + h4 * 8;
    const unsigned short* ap1 = ap0 + 16 * 256;
    const unsigned short* wb0 = Wo + (n0 + cl) * 256 + h4 * 8;

    f32x4 acc00 = {0.f, 0.f, 0.f, 0.f}, acc10 = {0.f, 0.f, 0.f, 0.f};
#pragma unroll
    for (int ksi = 0; ksi < 8; ksi++) {
        bf16x8 a0 = ld_bf8(ap0 + ksi * 32);
        bf16x8 a1 = ld_bf8(ap1 + ksi * 32);
        bf16x8 b0 = ld_bf8(wb0 + ksi * 32);
        acc00 = MFMA16(a0, b0, acc00, 0, 0, 0);
        acc10 = MFMA16(a1, b0, acc10, 0, 0, 0);
    }
#pragma unroll
    for (int am = 0; am < 2; am++) {
#pragma unroll
        for (int r = 0; r < 4; r++) {
            const int cm = m0 + am * 16 + h4 * 4 + r;
            out[cm * 256 + n0 + cl] = am ? acc10[r] : acc00[r];
        }
    }
}

// ---- fallback oproj (f32 Wo, inline cvt) ----
__global__ __launch_bounds__(256) void oproj_f32_kernel(
    const unsigned short* __restrict__ An, const float* __restrict__ Wo,
    float* __restrict__ out) {
    const int lane = threadIdx.x & 63;
    const int w = threadIdx.x >> 6;
    const int cl = lane & 15;
    const int h4 = lane >> 4;
    const int t = blockIdx.x * 4 + w;
    const int m0 = (t >> 3) * 32;
    const int n0 = (t & 7) * 32;

    const unsigned short* ap0 = An + (m0 + cl) * 256 + h4 * 8;
    const unsigned short* ap1 = ap0 + 16 * 256;
    const float* wb0 = Wo + (n0 + cl) * 256 + h4 * 8;
    const float* wb1 = wb0 + 16 * 256;

    f32x4 acc00 = {0.f, 0.f, 0.f, 0.f}, acc01 = {0.f, 0.f, 0.f, 0.f};
    f32x4 acc10 = {0.f, 0.f, 0.f, 0.f}, acc11 = {0.f, 0.f, 0.f, 0.f};
#pragma unroll
    for (int ksi = 0; ksi < 8; ksi++) {
        bf16x8 a0 = ld_bf8(ap0 + ksi * 32);
        bf16x8 a1 = ld_bf8(ap1 + ksi * 32);
        bf16x8 b0 = cvt_f8(*(const f32x8*)(wb0 + ksi * 32));
        bf16x8 b1 = cvt_f8(*(const f32x8*)(wb1 + ksi * 32));
        acc00 = MFMA16(a0, b0, acc00, 0, 0, 0);
        acc01 = MFMA16(a0, b1, acc01, 0, 0, 0);
        acc10 = MFMA16(a1, b0, acc10, 0, 0, 0);
        acc11 = MFMA16(a1, b1, acc11, 0, 0, 0);
    }
#pragma unroll
    for (int am = 0; am < 2; am++) {
#pragma unroll
        for (int r = 0; r < 4; r++) {
            const int cm = m0 + am * 16 + h4 * 4 + r;
#pragma unroll
            for (int bn = 0; bn < 2; bn++) {
                float v = am ? (bn ? acc11[r] : acc10[r]) : (bn ? acc01[r] : acc00[r]);
                out[cm * 256 + n0 + bn * 16 + cl] = v;
            }
        }
    }
}

extern "C" void kernel_launch(void* const* d_in, const int* in_sizes, int n_in,
                              void* d_out, int out_size, void* d_ws, size_t ws_size,
                              hipStream_t stream) {
    const float* query = (const float*)d_in[0];
    const float* key_ = (const float*)d_in[1];
    const float* value = (const float*)d_in[2];
    const float* radial = (const float*)d_in[3];
    const float* Wq = (const float*)d_in[4];
    const float* Wk = (const float*)d_in[5];
    const float* Wv = (const float*)d_in[6];
    const float* Wo = (const float*)d_in[7];

    const size_t MB = 1u << 20;
    uint8_t* base = (uint8_t*)d_ws;
    unsigned short* wq = (unsigned short*)(base + 0 * MB);
    unsigned short* wk = (unsigned short*)(base + 2 * MB);
    unsigned short* wv = (unsigned short*)(base + 4 * MB);
    unsigned short* wa = (unsigned short*)(base + 6 * MB);

    if (ws_size >= (size_t)(15.5 * 1024 * 1024)) {
        unsigned short* bX0 = (unsigned short*)(base + 8 * MB);
        unsigned short* bX1 = (unsigned short*)(base + 10 * MB);
        unsigned short* bX2 = (unsigned short*)(base + 12 * MB);
        unsigned short* bWq = (unsigned short*)(base + 14 * MB);
        unsigned short* bWk = (unsigned short*)(base + 14 * MB + 128 * 1024);
        unsigned short* bWv = (unsigned short*)(base + 14 * MB + 256 * 1024);
        unsigned short* bWo = (unsigned short*)(base + 14 * MB + 384 * 1024);
        precvt_kernel<<<1664, 256, 0, stream>>>(query, key_, value, Wq, Wk, Wv, Wo,
                                                bX0, bX1, bX2, bWq, bWk, bWv, bWo);
        proj_bf16_kernel<<<dim3(256, 3), 256, 0, stream>>>(bX0, bX1, bX2, bWq, bWk, bWv,
                                                           radial, wq, wk, wv);
        attn_kernel<<<256, 512, 0, stream>>>(wq, wk, wv, wa);
        oproj_bf16_kernel<<<512, 256, 0, stream>>>(wa, bWo, (float*)d_out);
    } else {
        proj_f32_kernel<<<dim3(256, 3), 256, 0, stream>>>(query, key_, value, Wq, Wk, Wv,
                                                          radial, wq, wk, wv);
        attn_kernel<<<256, 512, 0, stream>>>(wq, wk, wv, wa);
        oproj_f32_kernel<<<256, 256, 0, stream>>>(wa, Wo, (float*)d_out);
    }
}